// Round 1
// baseline (1539.229 us; speedup 1.0000x reference)
//
#include <hip/hip_runtime.h>
#include <math.h>

#define WL_LAYERS 3
#define HSLOTS (1u << 18)
#define HMASK  (HSLOTS - 1u)

typedef unsigned long long u64;

__device__ __forceinline__ u64 mix64(u64 x) {
    x += 0x9e3779b97f4a7c15ULL;
    x = (x ^ (x >> 30)) * 0xbf58476d1ce4e5b9ULL;
    x = (x ^ (x >> 27)) * 0x94d049bb133111ebULL;
    return x ^ (x >> 31);
}

// ---- zero the (large) output buffer, float4-vectorized ----
__global__ void k_zero_out(float* __restrict__ p, long long n) {
    long long i = (long long)blockIdx.x * blockDim.x + threadIdx.x;
    long long stride = (long long)gridDim.x * blockDim.x;
    long long n4 = n >> 2;
    float4* p4 = (float4*)p;
    for (long long j = i; j < n4; j += stride) p4[j] = make_float4(0.f, 0.f, 0.f, 0.f);
    if (i < (n & 3)) p[(n4 << 2) + i] = 0.f;
}

// ---- once-per-launch init: zero degrees, base[0]=0 ----
__global__ void k_init(int* __restrict__ deg, long long* __restrict__ scalars, int n) {
    int i = blockIdx.x * blockDim.x + threadIdx.x;
    int stride = gridDim.x * blockDim.x;
    for (int j = i; j < n; j += stride) deg[j] = 0;
    if (i == 0) scalars[3] = 0;  // base offset of layer 0
}

__global__ void k_deg(const int* __restrict__ dst, int* __restrict__ deg, int E) {
    int e = blockIdx.x * blockDim.x + threadIdx.x;
    if (e < E) atomicAdd(&deg[dst[e]], 1);
}

// ---- per-layer init: hash accumulators, hash table, group-min, row sumsq ----
__global__ void k_layer_init(u64* __restrict__ hacc, u64* __restrict__ ktab,
                             int* __restrict__ gmin, float* __restrict__ sumsq, int n) {
    int i = blockIdx.x * blockDim.x + threadIdx.x;
    int stride = gridDim.x * blockDim.x;
    int twoN = 2 * n;
    for (int j = i; j < twoN; j += stride) hacc[j] = 0ULL;
    for (int j = i; j < (int)(2u * HSLOTS); j += stride) ktab[j] = 0ULL;
    for (int j = i; j < (int)HSLOTS; j += stride) gmin[j] = 0x7fffffff;
    for (int j = i; j < n; j += stride) sumsq[j] = 0.f;
}

// ---- commutative multiset hash: per edge, add mix(color[src]) into dst's two accumulators.
// u64 wraparound add is associative+commutative -> deterministic despite atomics. ----
__global__ void k_edge_hash(const int* __restrict__ src, const int* __restrict__ dst,
                            const int* __restrict__ col,
                            u64* __restrict__ h1, u64* __restrict__ h2, int E) {
    int e = blockIdx.x * blockDim.x + threadIdx.x;
    if (e >= E) return;
    int d = dst[e];
    u64 c = (u64)(unsigned)col[src[e]];
    atomicAdd(&h1[d], mix64(c ^ 0x5bf03635c1d4aeb1ULL));
    atomicAdd(&h2[d], mix64(c ^ 0x2b7e151628aed2a5ULL));
}

// ---- group nodes by 128-bit signature via lock-free double-CAS table ----
__global__ void k_insert(const int* __restrict__ col, const int* __restrict__ deg,
                         const u64* __restrict__ h1acc, const u64* __restrict__ h2acc,
                         u64* __restrict__ k1, u64* __restrict__ k2,
                         int* __restrict__ gmin, int* __restrict__ nodeslot, int n) {
    int i = blockIdx.x * blockDim.x + threadIdx.x;
    if (i >= n) return;
    u64 b = mix64((u64)(unsigned)col[i] + 0x0123456789abcdefULL);
    u64 c = mix64((u64)(unsigned)deg[i] + 0xfedcba9876543210ULL);
    u64 h1 = mix64(h1acc[i] + b * 0x9e3779b97f4a7c15ULL + c * 0xc2b2ae3d27d4eb4fULL);
    u64 h2 = mix64(h2acc[i] ^ (b * 0xff51afd7ed558ccdULL) ^ (c * 0xc4ceb9fe1a85ec53ULL)
                   ^ 0x9e3779b97f4a7c15ULL);
    if (!h1) h1 = 1;
    if (!h2) h2 = 1;
    unsigned slot = (unsigned)h1 & HMASK;
    for (;;) {
        u64 p1 = atomicCAS(&k1[slot], 0ULL, h1);
        if (p1 == 0ULL || p1 == h1) {
            u64 p2 = atomicCAS(&k2[slot], 0ULL, h2);
            if (p2 == 0ULL || p2 == h2) break;  // matched/claimed both halves
        }
        slot = (slot + 1) & HMASK;  // different signature here -> linear probe
    }
    nodeslot[i] = slot;
    atomicMin(&gmin[slot], i);
}

__global__ void k_flag(const int* __restrict__ nodeslot, const int* __restrict__ gmin,
                       int* __restrict__ flag, int n) {
    int i = blockIdx.x * blockDim.x + threadIdx.x;
    if (i < n) flag[i] = (gmin[nodeslot[i]] == i) ? 1 : 0;
}

// ---- exclusive scan (1024 elems/block: 256 threads x 4) ----
__global__ void k_scan1(const int* __restrict__ in, int* __restrict__ out,
                        int* __restrict__ bsum, int n) {
    __shared__ int s[256];
    int t = threadIdx.x;
    int idx0 = blockIdx.x * 1024 + t * 4;
    int v[4];
    int sum = 0;
#pragma unroll
    for (int j = 0; j < 4; ++j) {
        int ii = idx0 + j;
        v[j] = (ii < n) ? in[ii] : 0;
        sum += v[j];
    }
    s[t] = sum;
    __syncthreads();
    for (int off = 1; off < 256; off <<= 1) {
        int x = (t >= off) ? s[t - off] : 0;
        __syncthreads();
        s[t] += x;
        __syncthreads();
    }
    int run = s[t] - sum;  // exclusive across threads
#pragma unroll
    for (int j = 0; j < 4; ++j) {
        int ii = idx0 + j;
        if (ii < n) out[ii] = run;
        run += v[j];
    }
    if (t == 255) bsum[blockIdx.x] = s[255];
}

// single-thread scan of block sums (<=98 blocks); also publishes nc[layer] and base[layer+1]
__global__ void k_scan2(int* __restrict__ bsum, int nb, long long* __restrict__ scalars,
                        int layer, const int* __restrict__ batch, int n) {
    if (blockIdx.x == 0 && threadIdx.x == 0) {
        long long run = 0;
        for (int b = 0; b < nb; ++b) {
            int t = bsum[b];
            bsum[b] = (int)run;
            run += t;
        }
        scalars[layer] = run;  // nc for this layer
        long long bsize = (long long)batch[n - 1] + 1;  // batch is sorted
        scalars[3 + layer + 1] = scalars[3 + layer] + bsize * run;
    }
}

__global__ void k_scan3(int* __restrict__ out, const int* __restrict__ bsum, int n) {
    int add = bsum[blockIdx.x];
    int idx0 = blockIdx.x * 1024 + threadIdx.x * 4;
#pragma unroll
    for (int j = 0; j < 4; ++j) {
        int ii = idx0 + j;
        if (ii < n) out[ii] += add;
    }
}

// new color = first-occurrence rank of the node's group
__global__ void k_newcolor(const int* __restrict__ nodeslot, const int* __restrict__ gmin,
                           const int* __restrict__ rank, int* __restrict__ colq, int n) {
    int i = blockIdx.x * blockDim.x + threadIdx.x;
    if (i < n) colq[i] = rank[gmin[nodeslot[i]]];
}

// scatter weights; incremental row-sumsq via returned old value: sum of (2*old*w + w^2) = cnt^2 (exact ints)
__global__ void k_hist(const int* __restrict__ batch, const int* __restrict__ col,
                       const float* __restrict__ w, float* __restrict__ out,
                       float* __restrict__ sumsq, float* __restrict__ oldv,
                       const long long* __restrict__ scalars, int layer, int n) {
    int i = blockIdx.x * blockDim.x + threadIdx.x;
    if (i >= n) return;
    int r = batch[i];
    long long nc = scalars[layer];
    long long base = scalars[3 + layer];
    long long idx = base + (long long)r * nc + col[i];
    float wi = w[i];
    float old = atomicAdd(&out[idx], wi);
    oldv[i] = old;
    atomicAdd(&sumsq[r], 2.f * old * wi + wi * wi);
}

// normalize: only the unique "owner" node per cell (saw old==0) rewrites it -> sparse, race-free
__global__ void k_norm(const int* __restrict__ batch, const int* __restrict__ col,
                       float* __restrict__ out, const float* __restrict__ sumsq,
                       const float* __restrict__ oldv,
                       const long long* __restrict__ scalars, int layer, int n) {
    int i = blockIdx.x * blockDim.x + threadIdx.x;
    if (i >= n) return;
    if (oldv[i] != 0.f) return;
    int r = batch[i];
    long long nc = scalars[layer];
    long long base = scalars[3 + layer];
    long long idx = base + (long long)r * nc + col[i];
    out[idx] = out[idx] / sqrtf(sumsq[r]);
}

extern "C" void kernel_launch(void* const* d_in, const int* in_sizes, int n_in,
                              void* d_out, int out_size, void* d_ws, size_t ws_size,
                              hipStream_t stream) {
    const int* x = (const int*)d_in[0];
    const int* ei = (const int*)d_in[1];
    const int* batch = (const int*)d_in[2];
    const float* w = (const float*)d_in[3];
    int N = in_sizes[0];
    int E = in_sizes[1] / 2;
    const int* src = ei;
    const int* dst = ei + E;

    // carve workspace (~10.1 MB for N=100K, H=2^18)
    char* p = (char*)d_ws;
    u64* hacc = (u64*)p;            p += (size_t)2 * N * 8;       // h1acc[N], h2acc[N]
    u64* ktab = (u64*)p;            p += (size_t)2 * HSLOTS * 8;  // k1[H], k2[H]
    long long* scalars = (long long*)p; p += 8 * 8;               // nc[3], base[4]
    int* deg      = (int*)p;        p += (size_t)N * 4;
    int* gmin     = (int*)p;        p += (size_t)HSLOTS * 4;
    int* nodeslot = (int*)p;        p += (size_t)N * 4;
    int* flag     = (int*)p;        p += (size_t)N * 4;
    int* rankv    = (int*)p;        p += (size_t)N * 4;
    int* colA     = (int*)p;        p += (size_t)N * 4;
    int* colB     = (int*)p;        p += (size_t)N * 4;
    int* bsum     = (int*)p;        p += 1024 * 4;
    float* oldv   = (float*)p;      p += (size_t)N * 4;
    float* sumsq  = (float*)p;      p += (size_t)N * 4;
    if ((size_t)(p - (char*)d_ws) > ws_size) return;  // insufficient scratch -> visible failure

    int gN = (N + 255) / 256;
    int gE = (E + 255) / 256;
    int nb = (N + 1023) / 1024;

    k_zero_out<<<4096, 256, 0, stream>>>((float*)d_out, (long long)out_size);
    k_init<<<gN, 256, 0, stream>>>(deg, scalars, N);
    k_deg<<<gE, 256, 0, stream>>>(dst, deg, E);

    const int* cur = x;
    int* nxt = colA;
    for (int l = 0; l < WL_LAYERS; ++l) {
        k_layer_init<<<2048, 256, 0, stream>>>(hacc, ktab, gmin, sumsq, N);
        k_edge_hash<<<gE, 256, 0, stream>>>(src, dst, cur, hacc, hacc + N, E);
        k_insert<<<gN, 256, 0, stream>>>(cur, deg, hacc, hacc + N, ktab, ktab + HSLOTS,
                                         gmin, nodeslot, N);
        k_flag<<<gN, 256, 0, stream>>>(nodeslot, gmin, flag, N);
        k_scan1<<<nb, 256, 0, stream>>>(flag, rankv, bsum, N);
        k_scan2<<<1, 256, 0, stream>>>(bsum, nb, scalars, l, batch, N);
        k_scan3<<<nb, 256, 0, stream>>>(rankv, bsum, N);
        k_newcolor<<<gN, 256, 0, stream>>>(nodeslot, gmin, rankv, nxt, N);
        k_hist<<<gN, 256, 0, stream>>>(batch, nxt, w, (float*)d_out, sumsq, oldv,
                                       scalars, l, N);
        k_norm<<<gN, 256, 0, stream>>>(batch, nxt, (float*)d_out, sumsq, oldv,
                                       scalars, l, N);
        cur = nxt;
        nxt = (l == 0) ? colB : colA;
    }
}

// Round 2
// 964.347 us; speedup vs baseline: 1.5961x; 1.5961x over previous
//
#include <hip/hip_runtime.h>
#include <math.h>

#define WL_LAYERS 3
#define HSLOTS (1u << 18)
#define HMASK  (HSLOTS - 1u)

typedef unsigned long long u64;

__device__ __forceinline__ u64 mix64(u64 x) {
    x += 0x9e3779b97f4a7c15ULL;
    x = (x ^ (x >> 30)) * 0xbf58476d1ce4e5b9ULL;
    x = (x ^ (x >> 27)) * 0x94d049bb133111ebULL;
    return x ^ (x >> 31);
}

// once: zero deg + hsum, base[0]=0
__global__ void k_init(int* __restrict__ deg, u64* __restrict__ hsum,
                       long long* __restrict__ scalars, int n) {
    int i = blockIdx.x * blockDim.x + threadIdx.x;
    int st = gridDim.x * blockDim.x;
    for (int j = i; j < n; j += st) { deg[j] = 0; hsum[j] = 0ULL; }
    if (i == 0) scalars[3] = 0;
}

// per layer: commutative multiset hash per edge (+deg on layer 0),
// fused zeroing of this layer's table/gmin/sumsq, and (layer 0) of d_out.
// u64 wraparound atomicAdd is associative+commutative -> deterministic.
__global__ void k_edge(const int* __restrict__ src, const int* __restrict__ dst,
                       const int* __restrict__ col, u64* __restrict__ hsum,
                       int* __restrict__ deg, int addDeg,
                       u64* __restrict__ ktab, int* __restrict__ gmin,
                       float* __restrict__ sumsq, int n,
                       float* __restrict__ zbuf, long long zn, int E) {
    int tid = blockIdx.x * blockDim.x + threadIdx.x;
    int T = gridDim.x * blockDim.x;
    for (int j = tid; j < (int)HSLOTS; j += T) { ktab[j] = 0ULL; gmin[j] = 0x7fffffff; }
    for (int j = tid; j < n; j += T) sumsq[j] = 0.f;
    if (zn > 0) {  // hide the big output zero-fill under this latency-bound kernel
        long long n4 = zn >> 2;
        float4* z4 = (float4*)zbuf;
        for (long long j = tid; j < n4; j += (long long)T)
            z4[j] = make_float4(0.f, 0.f, 0.f, 0.f);
        if (tid < (int)(zn & 3)) zbuf[(n4 << 2) + tid] = 0.f;
    }
    if (tid < E) {
        int d = dst[tid];
        u64 c = (u64)(unsigned)col[src[tid]];
        atomicAdd(&hsum[d], mix64(c ^ 0x5bf03635c1d4aeb1ULL));
        if (addDeg) atomicAdd(&deg[d], 1);
    }
}

// group nodes by 64-bit signature (sum-hash + own color + degree) via CAS table
__global__ void k_insert(const int* __restrict__ col, const int* __restrict__ deg,
                         const u64* __restrict__ hsum, u64* __restrict__ ktab,
                         int* __restrict__ gmin, int* __restrict__ nodeslot, int n) {
    int i = blockIdx.x * blockDim.x + threadIdx.x;
    if (i >= n) return;
    u64 b = mix64((u64)(unsigned)col[i] + 0x0123456789abcdefULL);
    u64 c = mix64((u64)(unsigned)deg[i] + 0xfedcba9876543210ULL);
    u64 sig = mix64(hsum[i] + b * 0x9e3779b97f4a7c15ULL + c * 0xc2b2ae3d27d4eb4fULL);
    if (!sig) sig = 1;
    unsigned slot = (unsigned)sig & HMASK;
    for (;;) {
        u64 p = atomicCAS(&ktab[slot], 0ULL, sig);
        if (p == 0ULL || p == sig) break;
        slot = (slot + 1) & HMASK;
    }
    nodeslot[i] = slot;
    atomicMin(&gmin[slot], i);
}

// fused flag + block-local exclusive scan (1024 elems/block)
__global__ void k_scan1(const int* __restrict__ nodeslot, const int* __restrict__ gmin,
                        int* __restrict__ rankv, int* __restrict__ bsum, int n) {
    __shared__ int s[256];
    int t = threadIdx.x;
    int idx0 = blockIdx.x * 1024 + t * 4;
    int v[4];
    int sum = 0;
#pragma unroll
    for (int j = 0; j < 4; ++j) {
        int ii = idx0 + j;
        v[j] = (ii < n && gmin[nodeslot[ii]] == ii) ? 1 : 0;
        sum += v[j];
    }
    s[t] = sum;
    __syncthreads();
    for (int off = 1; off < 256; off <<= 1) {
        int x = (t >= off) ? s[t - off] : 0;
        __syncthreads();
        s[t] += x;
        __syncthreads();
    }
    int run = s[t] - sum;
#pragma unroll
    for (int j = 0; j < 4; ++j) {
        int ii = idx0 + j;
        if (ii < n) rankv[ii] = run;
        run += v[j];
    }
    if (t == 255) bsum[blockIdx.x] = s[255];
}

// parallel scan of block sums (nb <= 256); publishes nc[layer], base[layer+1]
__global__ void k_scan2(int* __restrict__ bsum, int nb, long long* __restrict__ scalars,
                        int layer, const int* __restrict__ batch, int n) {
    __shared__ int s[256];
    int t = threadIdx.x;
    int v = (t < nb) ? bsum[t] : 0;
    s[t] = v;
    __syncthreads();
    for (int off = 1; off < 256; off <<= 1) {
        int x = (t >= off) ? s[t - off] : 0;
        __syncthreads();
        s[t] += x;
        __syncthreads();
    }
    if (t < nb) bsum[t] = s[t] - v;  // exclusive
    if (t == 255) {
        long long total = s[255];
        scalars[layer] = total;                          // nc
        long long bsize = (long long)batch[n - 1] + 1;   // batch sorted
        scalars[4 + layer] = scalars[3 + layer] + bsize * total;
    }
}

// leaders publish their group's appearance-order color (fused scan3 + leader write)
__global__ void k_slotcolor(const int* __restrict__ nodeslot, const int* __restrict__ gmin,
                            const int* __restrict__ rankv, const int* __restrict__ bsum,
                            int* __restrict__ slotcolor, int n) {
    int add = bsum[blockIdx.x];
    int idx0 = blockIdx.x * 1024 + threadIdx.x * 4;
#pragma unroll
    for (int j = 0; j < 4; ++j) {
        int ii = idx0 + j;
        if (ii < n) {
            int sl = nodeslot[ii];
            if (gmin[sl] == ii) slotcolor[sl] = rankv[ii] + add;
        }
    }
}

// new color lookup + histogram scatter; incremental row-sumsq (exact-integer fp adds)
__global__ void k_hist(const int* __restrict__ batch, const int* __restrict__ nodeslot,
                       const int* __restrict__ slotcolor, int* __restrict__ nxt,
                       const float* __restrict__ w, float* __restrict__ out,
                       float* __restrict__ sumsq, float* __restrict__ oldv,
                       const long long* __restrict__ scalars, int layer, int n) {
    int i = blockIdx.x * blockDim.x + threadIdx.x;
    if (i >= n) return;
    int c = slotcolor[nodeslot[i]];
    nxt[i] = c;
    int r = batch[i];
    long long idx = scalars[3 + layer] + (long long)r * scalars[layer] + c;
    float wi = w[i];
    float old = atomicAdd(&out[idx], wi);
    oldv[i] = old;
    atomicAdd(&sumsq[r], 2.f * old * wi + wi * wi);
}

// owners (saw old==0) normalize their cell; fused: zero hsum for next layer
__global__ void k_norm(const int* __restrict__ batch, const int* __restrict__ col,
                       float* __restrict__ out, const float* __restrict__ sumsq,
                       const float* __restrict__ oldv,
                       const long long* __restrict__ scalars, int layer,
                       u64* __restrict__ hsum, int n) {
    int i = blockIdx.x * blockDim.x + threadIdx.x;
    if (i >= n) return;
    hsum[i] = 0ULL;
    if (oldv[i] != 0.f) {
        return;
    }
    int r = batch[i];
    long long idx = scalars[3 + layer] + (long long)r * scalars[layer] + col[i];
    out[idx] = out[idx] / sqrtf(sumsq[r]);
}

extern "C" void kernel_launch(void* const* d_in, const int* in_sizes, int n_in,
                              void* d_out, int out_size, void* d_ws, size_t ws_size,
                              hipStream_t stream) {
    const int* x = (const int*)d_in[0];
    const int* ei = (const int*)d_in[1];
    const int* batch = (const int*)d_in[2];
    const float* w = (const float*)d_in[3];
    int N = in_sizes[0];
    int E = in_sizes[1] / 2;
    const int* src = ei;
    const int* dst = ei + E;

    // workspace carve (~7.6 MB)
    char* p = (char*)d_ws;
    u64* hsum = (u64*)p;              p += (size_t)N * 8;
    u64* ktab = (u64*)p;              p += (size_t)HSLOTS * 8;
    long long* scalars = (long long*)p; p += 8 * 8;
    int* deg      = (int*)p;          p += (size_t)N * 4;
    int* gmin     = (int*)p;          p += (size_t)HSLOTS * 4;
    int* nodeslot = (int*)p;          p += (size_t)N * 4;
    int* rankv    = (int*)p;          p += (size_t)N * 4;
    int* colA     = (int*)p;          p += (size_t)N * 4;
    int* colB     = (int*)p;          p += (size_t)N * 4;
    int* slotcol  = (int*)p;          p += (size_t)HSLOTS * 4;
    int* bsum     = (int*)p;          p += 1024 * 4;
    float* oldv   = (float*)p;        p += (size_t)N * 4;
    float* sumsq  = (float*)p;        p += (size_t)N * 4;
    if ((size_t)(p - (char*)d_ws) > ws_size) return;

    int gN = (N + 255) / 256;
    int gE = (E + 255) / 256;
    int nb = (N + 1023) / 1024;

    k_init<<<gN, 256, 0, stream>>>(deg, hsum, scalars, N);

    const int* cur = x;
    int* nxt = colA;
    for (int l = 0; l < WL_LAYERS; ++l) {
        k_edge<<<gE, 256, 0, stream>>>(src, dst, cur, hsum, deg, (l == 0) ? 1 : 0,
                                       ktab, gmin, sumsq, N, (float*)d_out,
                                       (l == 0) ? (long long)out_size : 0LL, E);
        k_insert<<<gN, 256, 0, stream>>>(cur, deg, hsum, ktab, gmin, nodeslot, N);
        k_scan1<<<nb, 256, 0, stream>>>(nodeslot, gmin, rankv, bsum, N);
        k_scan2<<<1, 256, 0, stream>>>(bsum, nb, scalars, l, batch, N);
        k_slotcolor<<<nb, 256, 0, stream>>>(nodeslot, gmin, rankv, bsum, slotcol, N);
        k_hist<<<gN, 256, 0, stream>>>(batch, nodeslot, slotcol, nxt, w, (float*)d_out,
                                       sumsq, oldv, scalars, l, N);
        k_norm<<<gN, 256, 0, stream>>>(batch, nxt, (float*)d_out, sumsq, oldv,
                                       scalars, l, hsum, N);
        cur = nxt;
        nxt = (l == 0) ? colB : colA;
    }
}

// Round 3
// 502.378 us; speedup vs baseline: 3.0639x; 1.9196x over previous
//
#include <hip/hip_runtime.h>
#include <math.h>

#define WL_LAYERS 3
#define HSLOTS (1u << 18)
#define HMASK  (HSLOTS - 1u)

typedef unsigned long long u64;

__device__ __forceinline__ u64 mix64(u64 x) {
    x += 0x9e3779b97f4a7c15ULL;
    x = (x ^ (x >> 30)) * 0xbf58476d1ce4e5b9ULL;
    x = (x ^ (x >> 27)) * 0x94d049bb133111ebULL;
    return x ^ (x >> 31);
}

// zero deg + cursor, base[0]=0
__global__ void k_setup(int* __restrict__ deg, int* __restrict__ cursor,
                        long long* __restrict__ scalars, int n) {
    int i = blockIdx.x * blockDim.x + threadIdx.x;
    int st = gridDim.x * blockDim.x;
    for (int j = i; j < n; j += st) { deg[j] = 0; cursor[j] = 0; }
    if (i == 0) scalars[3] = 0;
}

// in-degree count; fused: zero layer-0 tables + the 614MB d_out (hidden under atomics)
__global__ void k_count(const int* __restrict__ dst, int* __restrict__ deg,
                        u64* __restrict__ ktab, int* __restrict__ gmin,
                        float* __restrict__ sumsq, int n,
                        float* __restrict__ zbuf, long long zn, int E) {
    int tid = blockIdx.x * blockDim.x + threadIdx.x;
    int T = gridDim.x * blockDim.x;
    for (int j = tid; j < (int)HSLOTS; j += T) { ktab[j] = 0ULL; gmin[j] = 0x7fffffff; }
    for (int j = tid; j < n; j += T) sumsq[j] = 0.f;
    long long n4 = zn >> 2;
    float4* z4 = (float4*)zbuf;
    for (long long j = tid; j < n4; j += (long long)T)
        z4[j] = make_float4(0.f, 0.f, 0.f, 0.f);
    if (tid < (int)(zn & 3)) zbuf[(n4 << 2) + tid] = 0.f;
    if (tid < E) atomicAdd(&deg[dst[tid]], 1);
}

// generic block-local exclusive scan of an int array (1024/block)
__global__ void k_scanA(const int* __restrict__ in, int* __restrict__ outp,
                        int* __restrict__ bsum, int n) {
    __shared__ int s[256];
    int t = threadIdx.x;
    int idx0 = blockIdx.x * 1024 + t * 4;
    int v[4];
    int sum = 0;
#pragma unroll
    for (int j = 0; j < 4; ++j) {
        int ii = idx0 + j;
        v[j] = (ii < n) ? in[ii] : 0;
        sum += v[j];
    }
    s[t] = sum;
    __syncthreads();
    for (int off = 1; off < 256; off <<= 1) {
        int x = (t >= off) ? s[t - off] : 0;
        __syncthreads();
        s[t] += x;
        __syncthreads();
    }
    int run = s[t] - sum;
#pragma unroll
    for (int j = 0; j < 4; ++j) {
        int ii = idx0 + j;
        if (ii < n) outp[ii] = run;
        run += v[j];
    }
    if (t == 255) bsum[blockIdx.x] = s[255];
}

// flags version: flag[i] = (gmin[nodeslot[i]] == i)
__global__ void k_scanF(const int* __restrict__ nodeslot, const int* __restrict__ gmin,
                        int* __restrict__ rankv, int* __restrict__ bsum, int n) {
    __shared__ int s[256];
    int t = threadIdx.x;
    int idx0 = blockIdx.x * 1024 + t * 4;
    int v[4];
    int sum = 0;
#pragma unroll
    for (int j = 0; j < 4; ++j) {
        int ii = idx0 + j;
        v[j] = (ii < n && gmin[nodeslot[ii]] == ii) ? 1 : 0;
        sum += v[j];
    }
    s[t] = sum;
    __syncthreads();
    for (int off = 1; off < 256; off <<= 1) {
        int x = (t >= off) ? s[t - off] : 0;
        __syncthreads();
        s[t] += x;
        __syncthreads();
    }
    int run = s[t] - sum;
#pragma unroll
    for (int j = 0; j < 4; ++j) {
        int ii = idx0 + j;
        if (ii < n) rankv[ii] = run;
        run += v[j];
    }
    if (t == 255) bsum[blockIdx.x] = s[255];
}

// scan block sums in place (nb<=256); if layer>=0 publish nc[layer], base[layer+1]
__global__ void k_scanB(int* __restrict__ bsum, int nb, long long* __restrict__ scalars,
                        int layer, const int* __restrict__ batch, int n) {
    __shared__ int s[256];
    int t = threadIdx.x;
    int v = (t < nb) ? bsum[t] : 0;
    s[t] = v;
    __syncthreads();
    for (int off = 1; off < 256; off <<= 1) {
        int x = (t >= off) ? s[t - off] : 0;
        __syncthreads();
        s[t] += x;
        __syncthreads();
    }
    if (t < nb) bsum[t] = s[t] - v;  // exclusive
    if (layer >= 0 && t == 255) {
        long long total = s[255];
        scalars[layer] = total;                         // nc
        long long bsize = (long long)batch[n - 1] + 1;  // batch sorted
        scalars[4 + layer] = scalars[3 + layer] + bsize * total;
    }
}

// CSR scatter: adjacency order is race-dependent, but every consumer is a
// commutative sum over the list -> output deterministic.
__global__ void k_scatter(const int* __restrict__ src, const int* __restrict__ dst,
                          const int* __restrict__ offp, const int* __restrict__ obsum,
                          int* __restrict__ cursor, int* __restrict__ adj, int E) {
    int e = blockIdx.x * blockDim.x + threadIdx.x;
    if (e >= E) return;
    int d = dst[e];
    int pos = atomicAdd(&cursor[d], 1);
    adj[offp[d] + obsum[d >> 10] + pos] = src[e];
}

// per-node gather hash (no atomics) + CAS-table group insert.
// fused: zero sumsq for this layer (consumed later by k_hist/k_norm).
__global__ void k_hashinsert(const int* __restrict__ col, const int* __restrict__ deg,
                             const int* __restrict__ offp, const int* __restrict__ obsum,
                             const int* __restrict__ adj, u64* __restrict__ ktab,
                             int* __restrict__ gmin, int* __restrict__ nodeslot,
                             float* __restrict__ sumsq, int n) {
    int i = blockIdx.x * blockDim.x + threadIdx.x;
    int T = gridDim.x * blockDim.x;
    for (int j = i; j < n; j += T) sumsq[j] = 0.f;
    if (i >= n) return;
    int s0 = offp[i] + obsum[i >> 10];
    int dg = deg[i];
    u64 h = 0ULL;
    for (int k = 0; k < dg; ++k) {
        u64 c = (u64)(unsigned)col[adj[s0 + k]];
        h += mix64(c ^ 0x5bf03635c1d4aeb1ULL);
    }
    u64 b = mix64((u64)(unsigned)col[i] + 0x0123456789abcdefULL);
    u64 c2 = mix64((u64)(unsigned)dg + 0xfedcba9876543210ULL);
    u64 sig = mix64(h + b * 0x9e3779b97f4a7c15ULL + c2 * 0xc2b2ae3d27d4eb4fULL);
    if (!sig) sig = 1;
    unsigned slot = (unsigned)sig & HMASK;
    for (;;) {
        u64 p = atomicCAS(&ktab[slot], 0ULL, sig);
        if (p == 0ULL || p == sig) break;
        slot = (slot + 1) & HMASK;
    }
    nodeslot[i] = slot;
    atomicMin(&gmin[slot], i);
}

// color = rank[gmin[slot]] + bsum[gmin>>10] computed per node (no leader pass);
// histogram scatter + LDS-aggregated row sumsq (exact-integer fp adds -> order-free)
__global__ void k_hist(const int* __restrict__ batch, const int* __restrict__ nodeslot,
                       const int* __restrict__ gmin, const int* __restrict__ rankv,
                       const int* __restrict__ bsum, int* __restrict__ nxt,
                       const float* __restrict__ w, float* __restrict__ out,
                       float* __restrict__ sumsq, float* __restrict__ oldv,
                       const long long* __restrict__ scalars, int layer, int n) {
    __shared__ float ssq[64];
    __shared__ int rbase_s;
    int t = threadIdx.x;
    int i = blockIdx.x * 256 + t;
    if (t < 64) ssq[t] = 0.f;
    if (t == 0) {
        int a = blockIdx.x * 256;
        rbase_s = batch[a < n ? a : n - 1];
    }
    __syncthreads();
    if (i < n) {
        int g = gmin[nodeslot[i]];
        int c = rankv[g] + bsum[g >> 10];
        nxt[i] = c;
        int r = batch[i];
        long long idx = scalars[3 + layer] + (long long)r * scalars[layer] + c;
        float wi = w[i];
        float old = atomicAdd(&out[idx], wi);
        oldv[i] = old;
        float val = 2.f * old * wi + wi * wi;
        int sl = r - rbase_s;
        if (sl >= 0 && sl < 64) atomicAdd(&ssq[sl], val);
        else atomicAdd(&sumsq[r], val);
    }
    __syncthreads();
    if (t < 64 && ssq[t] != 0.f) atomicAdd(&sumsq[rbase_s + t], ssq[t]);
}

// owners (saw old==0) normalize their cell; fused: zero ktab/gmin for next layer
__global__ void k_norm(const int* __restrict__ batch, const int* __restrict__ col,
                       float* __restrict__ out, const float* __restrict__ sumsq,
                       const float* __restrict__ oldv,
                       const long long* __restrict__ scalars, int layer,
                       u64* __restrict__ ktab, int* __restrict__ gmin, int n) {
    int i = blockIdx.x * blockDim.x + threadIdx.x;
    int T = gridDim.x * blockDim.x;
    for (int j = i; j < (int)HSLOTS; j += T) { ktab[j] = 0ULL; gmin[j] = 0x7fffffff; }
    if (i >= n) return;
    if (oldv[i] != 0.f) return;
    int r = batch[i];
    long long idx = scalars[3 + layer] + (long long)r * scalars[layer] + col[i];
    out[idx] = out[idx] / sqrtf(sumsq[r]);
}

extern "C" void kernel_launch(void* const* d_in, const int* in_sizes, int n_in,
                              void* d_out, int out_size, void* d_ws, size_t ws_size,
                              hipStream_t stream) {
    const int* x = (const int*)d_in[0];
    const int* ei = (const int*)d_in[1];
    const int* batch = (const int*)d_in[2];
    const float* w = (const float*)d_in[3];
    int N = in_sizes[0];
    int E = in_sizes[1] / 2;
    const int* src = ei;
    const int* dst = ei + E;

    // workspace carve (~20 MB)
    char* p = (char*)d_ws;
    u64* ktab = (u64*)p;                p += (size_t)HSLOTS * 8;
    long long* scalars = (long long*)p; p += 8 * 8;
    int* adj      = (int*)p;            p += (size_t)E * 4;
    int* deg      = (int*)p;            p += (size_t)N * 4;
    int* cursor   = (int*)p;            p += (size_t)N * 4;
    int* offp     = (int*)p;            p += (size_t)N * 4;
    int* gmin     = (int*)p;            p += (size_t)HSLOTS * 4;
    int* nodeslot = (int*)p;            p += (size_t)N * 4;
    int* rankv    = (int*)p;            p += (size_t)N * 4;
    int* colA     = (int*)p;            p += (size_t)N * 4;
    int* colB     = (int*)p;            p += (size_t)N * 4;
    int* bsum     = (int*)p;            p += 1024 * 4;
    int* obsum    = (int*)p;            p += 1024 * 4;
    float* oldv   = (float*)p;          p += (size_t)N * 4;
    float* sumsq  = (float*)p;          p += (size_t)N * 4;
    if ((size_t)(p - (char*)d_ws) > ws_size) return;

    int gN = (N + 255) / 256;
    int gE = (E + 255) / 256;
    int nb = (N + 1023) / 1024;

    k_setup<<<gN, 256, 0, stream>>>(deg, cursor, scalars, N);
    k_count<<<gE, 256, 0, stream>>>(dst, deg, ktab, gmin, sumsq, N,
                                    (float*)d_out, (long long)out_size, E);
    k_scanA<<<nb, 256, 0, stream>>>(deg, offp, obsum, N);
    k_scanB<<<1, 256, 0, stream>>>(obsum, nb, scalars, -1, batch, N);
    k_scatter<<<gE, 256, 0, stream>>>(src, dst, offp, obsum, cursor, adj, E);

    const int* cur = x;
    int* nxt = colA;
    for (int l = 0; l < WL_LAYERS; ++l) {
        k_hashinsert<<<gN, 256, 0, stream>>>(cur, deg, offp, obsum, adj, ktab, gmin,
                                             nodeslot, sumsq, N);
        k_scanF<<<nb, 256, 0, stream>>>(nodeslot, gmin, rankv, bsum, N);
        k_scanB<<<1, 256, 0, stream>>>(bsum, nb, scalars, l, batch, N);
        k_hist<<<gN, 256, 0, stream>>>(batch, nodeslot, gmin, rankv, bsum, nxt, w,
                                       (float*)d_out, sumsq, oldv, scalars, l, N);
        k_norm<<<gN, 256, 0, stream>>>(batch, nxt, (float*)d_out, sumsq, oldv,
                                       scalars, l, ktab, gmin, N);
        cur = nxt;
        nxt = (l == 0) ? colB : colA;
    }
}